// Round 1
// baseline (565.579 us; speedup 1.0000x reference)
//
#include <hip/hip_runtime.h>

// BlockTopK sparsify: per 8-float block of `score`, keep top-4 (stable
// ascending argsort drops the 4 smallest; among equal values the
// earlier-index ones are dropped first), out = x * mask.
//
// Memory-bound streaming kernel: 768 MiB traffic, roofline ~128 us @6.3TB/s.
//
// Layout: lane i <-> float4 i (perfectly unit-stride, 16B/lane — the
// coalescing sweet spot). An 8-float block spans a LANE PAIR (2k, 2k+1);
// the half-block scores are exchanged via __shfl_xor(.,1) (DPP quad-perm,
// register speed). This replaces the previous version's stride-32B lane
// pattern (each 128B line only half-used per instruction -> 2x TA/L1
// transactions on every load and store -> transaction-rate-bound at 1.4TB/s).

__global__ __launch_bounds__(256) void sparsify_topk_kernel(
    const float4* __restrict__ x4,
    const float4* __restrict__ s4,
    float4* __restrict__ o4,
    int n4)  // number of float4s = n/4
{
    int i = blockIdx.x * blockDim.x + threadIdx.x;
    if (i >= n4) return;

    float4 sv = s4[i];
    float4 xv = x4[i];

    float s[4] = {sv.x, sv.y, sv.z, sv.w};
    float x[4] = {xv.x, xv.y, xv.z, xv.w};

    // Partner lane (lane ^ 1) holds the other half of this 8-block.
    float t[4];
#pragma unroll
    for (int k = 0; k < 4; ++k)
        t[k] = __shfl_xor(s[k], 1);

    // Even lanes own block positions 0..3 (partner holds 4..7).
    // Odd lanes own block positions 4..7 (partner holds 0..3).
    // On a tie with a partner element, the partner's index precedes ours
    // iff we are the odd lane.
    const bool odd = (threadIdx.x & 1) != 0;

    float o[4];
#pragma unroll
    for (int k = 0; k < 4; ++k) {
        int rank = 0;  // # elements strictly before s[k] in stable asc. order
#pragma unroll
        for (int j = 0; j < 4; ++j) {
            if (j != k)
                rank += (s[j] < s[k]) || ((s[j] == s[k]) && (j < k));
            rank += (t[j] < s[k]) || ((t[j] == s[k]) && odd);
        }
        // stable ascending argsort drops the first 4 -> keep iff rank >= 4
        o[k] = (rank >= 4) ? x[k] : 0.0f;
    }

    o4[i] = make_float4(o[0], o[1], o[2], o[3]);
}

extern "C" void kernel_launch(void* const* d_in, const int* in_sizes, int n_in,
                              void* d_out, int out_size, void* d_ws, size_t ws_size,
                              hipStream_t stream) {
    const float4* x4 = (const float4*)d_in[0];
    const float4* s4 = (const float4*)d_in[1];
    float4* o4 = (float4*)d_out;

    int n = in_sizes[0];          // 8192*8192 = 67,108,864 floats
    int n4 = n / 4;               // 16,777,216 float4s

    const int threads = 256;
    int grid = (n4 + threads - 1) / threads;  // 65536 blocks
    sparsify_topk_kernel<<<grid, threads, 0, stream>>>(x4, s4, o4, n4);
}